// Round 1
// baseline (234.364 us; speedup 1.0000x reference)
//
#include <hip/hip_runtime.h>
#include <cstddef>

#define Bn 128
#define Pn 8732
#define Cn 21
#define On 16
#define MAGIC 0x13579BDFu

__device__ __forceinline__ void argmax_combine(float& v, int& p, float v2, int p2) {
  if (v2 > v || (v2 == v && p2 < p)) { v = v2; p = p2; }
}

// ---------------------------------------------------------------------------
// Kernel A: full-machine streaming pass over conf_data (94 MB) + IoU matching.
// 4096 waves = 128 images x 32 chunk-groups; wave w -> image (w & 127),
// chunks ci = (w>>7) + 32*i, i=0..4 (64 priors each; exactly covers 0..136).
// Barrier-free: per-wave LDS staging (coalesced float4), per-lane row compute.
// Outputs: ce0 (lse - x[0]), pack byte (bti | pos<<4), per-truth argmax keys
// via u64 atomicMax (key monotone in ov; tie -> smallest p; beats 0xAA poison).
// ---------------------------------------------------------------------------
__global__ __launch_bounds__(256) void stream_kernel(
    const float* __restrict__ conf, const float* __restrict__ dbox,
    const float* __restrict__ targets,
    float* __restrict__ ce0, unsigned char* __restrict__ pack,
    unsigned long long* __restrict__ keys) {
  const int wb = threadIdx.x >> 6, lane = threadIdx.x & 63;
  const int wave_g = blockIdx.x * 4 + wb;
  const int b = wave_g & 127;
  const int cg = wave_g >> 7;                    // 0..31

  __shared__ float4 s_row4[4][336];              // 5376 B per wave
  __shared__ float s_tt[4][On * 5];
  __shared__ float s_ar[4][On];

  // On*5 = 80 > 64 lanes: strided fill so elements 64..79 (truths 12-15) are
  // covered too. (Previous version wrote only 0..63 -> garbage IoU for j>=12.)
  #pragma unroll
  for (int i = lane; i < On * 5; i += 64)
    s_tt[wb][i] = targets[(size_t)b * On * 5 + i];
  if (lane < On) {
    float x1 = targets[(size_t)b * On * 5 + lane * 5 + 0];
    float y1 = targets[(size_t)b * On * 5 + lane * 5 + 1];
    float x2 = targets[(size_t)b * On * 5 + lane * 5 + 2];
    float y2 = targets[(size_t)b * On * 5 + lane * 5 + 3];
    s_ar[wb][lane] = (x2 - x1) * (y2 - y1);
  }

  float bestv[On]; int bestp[On];
  #pragma unroll
  for (int j = 0; j < On; j++) { bestv[j] = -1.0f; bestp[j] = 0x7fffffff; }

  #pragma unroll
  for (int i = 0; i < 5; i++) {
    const int ci = cg + 32 * i;
    if (ci >= 137) break;
    const int p0 = ci * 64;
    const int rows = min(64, Pn - p0);           // 64 or 28 (both %4==0)
    const int n4 = rows * Cn / 4;                // 336 or 147

    const float4* src = (const float4*)(conf + ((size_t)b * Pn + p0) * Cn);
    float4 v0, v1, v2, v3, v4, v5;
    // fully unrolled, predicated, independent -> deep MLP, coalesced 1KB/instr
    if (lane < n4)        v0 = src[lane];
    if (lane + 64 < n4)   v1 = src[lane + 64];
    if (lane + 128 < n4)  v2 = src[lane + 128];
    if (lane + 192 < n4)  v3 = src[lane + 192];
    if (lane + 256 < n4)  v4 = src[lane + 256];
    if (lane + 320 < n4)  v5 = src[lane + 320];
    if (lane < n4)        s_row4[wb][lane] = v0;
    if (lane + 64 < n4)   s_row4[wb][lane + 64] = v1;
    if (lane + 128 < n4)  s_row4[wb][lane + 128] = v2;
    if (lane + 192 < n4)  s_row4[wb][lane + 192] = v3;
    if (lane + 256 < n4)  s_row4[wb][lane + 256] = v4;
    if (lane + 320 < n4)  s_row4[wb][lane + 320] = v5;

    if (lane < rows) {
      const int p = p0 + lane;
      const float* x = (const float*)s_row4[wb] + lane * Cn;  // stride 21: 2-way, free
      float m = x[0];
      #pragma unroll
      for (int q = 1; q < Cn; q++) m = fmaxf(m, x[q]);
      float s = 0.0f;
      #pragma unroll
      for (int q = 0; q < Cn; q++) s += expf(x[q] - m);
      float lse = m + logf(s);
      ce0[(size_t)b * Pn + p] = lse - x[0];

      float4 d = ((const float4*)dbox)[p];
      float px1 = d.x - d.z * 0.5f, py1 = d.y - d.w * 0.5f;
      float px2 = d.x + d.z * 0.5f, py2 = d.y + d.w * 0.5f;
      float ap = d.z * d.w;
      float mv = -1.0f; int mj = 0;
      #pragma unroll
      for (int j = 0; j < On; j++) {
        float lx = fmaxf(s_tt[wb][j*5+0], px1);
        float ly = fmaxf(s_tt[wb][j*5+1], py1);
        float rx = fminf(s_tt[wb][j*5+2], px2);
        float ry = fminf(s_tt[wb][j*5+3], py2);
        float w = fmaxf(rx - lx, 0.0f), h = fmaxf(ry - ly, 0.0f);
        float inter = w * h;
        float ov = inter / (s_ar[wb][j] + ap - inter);
        if (ov > bestv[j]) { bestv[j] = ov; bestp[j] = p; }  // smallest p kept
        if (ov > mv) { mv = ov; mj = j; }                    // first max over j
      }
      pack[(size_t)b * Pn + p] =
          (unsigned char)(mj | ((mv >= 0.5f) ? 16 : 0));
    }
  }

  // per-truth argmax: wave shuffle reduce, then device atomicMax
  #pragma unroll
  for (int j = 0; j < On; j++) {
    float v = bestv[j]; int p = bestp[j];
    #pragma unroll
    for (int off = 32; off; off >>= 1) {
      float v2 = __shfl_down(v, off);
      int p2 = __shfl_down(p, off);
      argmax_combine(v, p, v2, p2);
    }
    if (lane == 0) {
      unsigned long long key;
      if (v < 0.0f) key = 0xC000000000000000ull;   // neutral, still beats poison
      else key = (((unsigned long long)(__float_as_uint(v) | 0xC0000000u)) << 32)
               | (unsigned long long)(0xFFFFFFFFu - (unsigned)p);
      atomicMax(&keys[b * On + j], key);
    }
  }
}

// ---------------------------------------------------------------------------
// Kernel B: per-image (128 blocks x 1024): forced matches, losses, register-
// based exact radix top-k, flag-based cross-block reduction (no extra node).
// ---------------------------------------------------------------------------
__global__ __launch_bounds__(1024) void reduce_kernel(
    const float* __restrict__ loc, const float* __restrict__ conf,
    const float* __restrict__ dbox, const float* __restrict__ targets,
    const float* __restrict__ ce0, const unsigned char* __restrict__ pack,
    const unsigned long long* __restrict__ keys,
    unsigned int* __restrict__ res, float* __restrict__ out) {
  const int b = blockIdx.x;
  const int tid = threadIdx.x;
  const int wave = tid >> 6, lane = tid & 63;

  __shared__ float s_t[On * 5];
  __shared__ int s_bp[On];
  __shared__ unsigned hist[16][256];
  __shared__ float s_redf[2][16];
  __shared__ int s_redi[16];
  __shared__ unsigned s_prefix;
  __shared__ int s_kk;
  __shared__ int s_np;

  if (tid < On * 5) s_t[tid] = targets[(size_t)b * On * 5 + tid];
  if (tid < On)
    s_bp[tid] = (int)(0xFFFFFFFFu - (unsigned)(keys[b * On + tid] & 0xFFFFFFFFull));
  __syncthreads();

  float ce_r[9];
  float my_loc = 0.0f, my_cep = 0.0f; int my_np = 0;
  #pragma unroll
  for (int sI = 0; sI < 9; sI++) {
    ce_r[sI] = 0.0f;
    const int p = tid + 1024 * sI;
    if (p < Pn) {
      unsigned char pk = pack[(size_t)b * Pn + p];
      float c0 = ce0[(size_t)b * Pn + p];
      int pos = pk >> 4;
      int bt = pk & 15;
      #pragma unroll
      for (int j = 0; j < On; j++)
        if (s_bp[j] == p) { bt = j; pos = 1; }      // ascending: last j wins
      ce_r[sI] = pos ? 0.0f : c0;
      if (pos) {
        my_np++;
        const float* t = &s_t[bt * 5];
        int c = (int)t[4] + 1;
        const float* row = conf + ((size_t)b * Pn + p) * Cn;
        my_cep += c0 + row[0] - row[c];             // lse - x[c]
        float4 d = ((const float4*)dbox)[p];
        float mx1 = t[0], my1 = t[1], mx2 = t[2], my2 = t[3];
        float g0 = ((mx1 + mx2) * 0.5f - d.x) / (0.1f * d.z);
        float g1 = ((my1 + my2) * 0.5f - d.y) / (0.1f * d.w);
        float g2 = logf((mx2 - mx1) / d.z) / 0.2f;
        float g3 = logf((my2 - my1) / d.w) / 0.2f;
        float4 ld = ((const float4*)loc)[(size_t)b * Pn + p];
        float g[4] = {g0, g1, g2, g3};
        float l[4] = {ld.x, ld.y, ld.z, ld.w};
        #pragma unroll
        for (int q = 0; q < 4; q++) {
          float ad = fabsf(l[q] - g[q]);
          my_loc += (ad < 1.0f) ? 0.5f * ad * ad : ad - 0.5f;
        }
      }
    }
  }

  {
    int np = my_np;
    #pragma unroll
    for (int off = 32; off; off >>= 1) np += __shfl_down(np, off);
    if (lane == 0) s_redi[wave] = np;
  }
  __syncthreads();
  if (tid == 0) {
    int np = 0;
    #pragma unroll
    for (int w = 0; w < 16; w++) np += s_redi[w];
    s_np = np;
  }
  __syncthreads();

  // exact k-th largest over register ce_neg values (all >= 0)
  const int k = min(s_np * 3, Pn);
  unsigned prefix = 0, maskb = 0;
  int kk = k;
  for (int shift = 24; shift >= 0; shift -= 8) {
    #pragma unroll
    for (int j = 0; j < 4; j++) hist[wave][lane * 4 + j] = 0;
    __syncthreads();
    #pragma unroll
    for (int sI = 0; sI < 9; sI++) {
      const int p = tid + 1024 * sI;
      if (p < Pn) {
        unsigned u = __float_as_uint(ce_r[sI]);
        if ((u & maskb) == prefix) atomicAdd(&hist[wave][(u >> shift) & 255u], 1u);
      }
    }
    __syncthreads();
    if (tid < 256) {
      unsigned c = 0;
      #pragma unroll
      for (int w = 0; w < 16; w++) c += hist[w][tid];
      hist[0][tid] = c;
    }
    __syncthreads();
    if (tid == 0) {
      int cum = 0, chosen = 0;
      for (int bin = 255; bin >= 0; bin--) {
        int c = (int)hist[0][bin];
        if (cum + c >= kk) { chosen = bin; break; }
        cum += c;
      }
      s_prefix = prefix | ((unsigned)chosen << shift);
      s_kk = kk - cum;
    }
    __syncthreads();
    prefix = s_prefix; kk = s_kk;
    maskb |= 255u << shift;
    __syncthreads();
  }
  float T = __uint_as_float(prefix);

  float sum_gt = 0.0f; int cnt_gt = 0;
  #pragma unroll
  for (int sI = 0; sI < 9; sI++) {
    const int p = tid + 1024 * sI;
    if (p < Pn) {
      float x = ce_r[sI];
      if (x > T) { sum_gt += x; cnt_gt++; }
    }
  }
  #pragma unroll
  for (int off = 32; off; off >>= 1) {
    sum_gt += __shfl_down(sum_gt, off);
    cnt_gt += __shfl_down(cnt_gt, off);
    my_loc += __shfl_down(my_loc, off);
    my_cep += __shfl_down(my_cep, off);
  }
  if (lane == 0) {
    s_redf[0][wave] = my_loc; s_redf[1][wave] = sum_gt + my_cep; s_redi[wave] = cnt_gt;
  }
  __syncthreads();
  if (tid == 0) {
    float ll = 0.0f, lc = 0.0f; int cg = 0;
    #pragma unroll
    for (int w = 0; w < 16; w++) {
      ll += s_redf[0][w]; lc += s_redf[1][w]; cg += s_redi[w];
    }
    lc += (k > 0) ? (float)(k - cg) * T : 0.0f;
    // post partials (device-scope atomics; visible cross-XCD), then flag
    atomicExch(&res[b * 4 + 0], __float_as_uint(ll));
    atomicExch(&res[b * 4 + 1], __float_as_uint(lc));
    atomicExch(&res[b * 4 + 2], (unsigned)s_np);
    __threadfence();
    atomicExch(&res[b * 4 + 3], MAGIC);
  }

  // block 0, wave 0: gather all 128 partials and finalize (no extra kernel)
  if (b == 0 && tid < 64) {
    float ll = 0.0f, lc = 0.0f; int np = 0;
    #pragma unroll
    for (int h = 0; h < 2; h++) {
      const int i = tid + 64 * h;
      while (atomicAdd(&res[i * 4 + 3], 0u) != MAGIC) { __builtin_amdgcn_s_sleep(8); }
      ll += __uint_as_float(atomicAdd(&res[i * 4 + 0], 0u));
      lc += __uint_as_float(atomicAdd(&res[i * 4 + 1], 0u));
      np += (int)atomicAdd(&res[i * 4 + 2], 0u);
    }
    #pragma unroll
    for (int off = 32; off; off >>= 1) {
      ll += __shfl_down(ll, off);
      lc += __shfl_down(lc, off);
      np += __shfl_down(np, off);
    }
    if (tid == 0) {
      float fN = (float)np;
      out[0] = ll / fN;
      out[1] = lc / fN;
    }
  }
}

extern "C" void kernel_launch(void* const* d_in, const int* in_sizes, int n_in,
                              void* d_out, int out_size, void* d_ws, size_t ws_size,
                              hipStream_t stream) {
  const float* loc_data  = (const float*)d_in[0];
  const float* conf_data = (const float*)d_in[1];
  const float* dbox      = (const float*)d_in[2];
  const float* targets   = (const float*)d_in[3];
  float* out = (float*)d_out;

  char* ws = (char*)d_ws;
  float* ce0 = (float*)ws;                                           // B*P f32
  unsigned char* pack = (unsigned char*)(ws + (size_t)Bn * Pn * 4);  // B*P bytes
  unsigned long long* keys =
      (unsigned long long*)(ws + (size_t)Bn * Pn * 5);               // B*16 u64
  unsigned int* res = (unsigned int*)(ws + (size_t)Bn * Pn * 5 + Bn * On * 8); // B*4 u32

  stream_kernel<<<1024, 256, 0, stream>>>(conf_data, dbox, targets, ce0, pack, keys);
  reduce_kernel<<<Bn, 1024, 0, stream>>>(loc_data, conf_data, dbox, targets,
                                         ce0, pack, keys, res, out);
}

// Round 2
// 201.422 us; speedup vs baseline: 1.1635x; 1.1635x over previous
//
#include <hip/hip_runtime.h>
#include <cstddef>

#define Bn 128
#define Pn 8732
#define Cn 21
#define On 16
#define MAGIC 0x13579BDFu

__device__ __forceinline__ void argmax_combine(float& v, int& p, float v2, int p2) {
  if (v2 > v || (v2 == v && p2 < p)) { v = v2; p = p2; }
}

// ---------------------------------------------------------------------------
// Kernel A: full-machine streaming pass over conf_data (94 MB) + IoU matching.
// (unchanged this round — isolate reduce_kernel change)
// ---------------------------------------------------------------------------
__global__ __launch_bounds__(256) void stream_kernel(
    const float* __restrict__ conf, const float* __restrict__ dbox,
    const float* __restrict__ targets,
    float* __restrict__ ce0, unsigned char* __restrict__ pack,
    unsigned long long* __restrict__ keys) {
  const int wb = threadIdx.x >> 6, lane = threadIdx.x & 63;
  const int wave_g = blockIdx.x * 4 + wb;
  const int b = wave_g & 127;
  const int cg = wave_g >> 7;                    // 0..31

  __shared__ float4 s_row4[4][336];              // 5376 B per wave
  __shared__ float s_tt[4][On * 5];
  __shared__ float s_ar[4][On];

  // On*5 = 80 > 64 lanes: strided fill covers elements 64..79 (truths 12-15).
  #pragma unroll
  for (int i = lane; i < On * 5; i += 64)
    s_tt[wb][i] = targets[(size_t)b * On * 5 + i];
  if (lane < On) {
    float x1 = targets[(size_t)b * On * 5 + lane * 5 + 0];
    float y1 = targets[(size_t)b * On * 5 + lane * 5 + 1];
    float x2 = targets[(size_t)b * On * 5 + lane * 5 + 2];
    float y2 = targets[(size_t)b * On * 5 + lane * 5 + 3];
    s_ar[wb][lane] = (x2 - x1) * (y2 - y1);
  }

  float bestv[On]; int bestp[On];
  #pragma unroll
  for (int j = 0; j < On; j++) { bestv[j] = -1.0f; bestp[j] = 0x7fffffff; }

  #pragma unroll
  for (int i = 0; i < 5; i++) {
    const int ci = cg + 32 * i;
    if (ci >= 137) break;
    const int p0 = ci * 64;
    const int rows = min(64, Pn - p0);           // 64 or 28 (both %4==0)
    const int n4 = rows * Cn / 4;                // 336 or 147

    const float4* src = (const float4*)(conf + ((size_t)b * Pn + p0) * Cn);
    float4 v0, v1, v2, v3, v4, v5;
    if (lane < n4)        v0 = src[lane];
    if (lane + 64 < n4)   v1 = src[lane + 64];
    if (lane + 128 < n4)  v2 = src[lane + 128];
    if (lane + 192 < n4)  v3 = src[lane + 192];
    if (lane + 256 < n4)  v4 = src[lane + 256];
    if (lane + 320 < n4)  v5 = src[lane + 320];
    if (lane < n4)        s_row4[wb][lane] = v0;
    if (lane + 64 < n4)   s_row4[wb][lane + 64] = v1;
    if (lane + 128 < n4)  s_row4[wb][lane + 128] = v2;
    if (lane + 192 < n4)  s_row4[wb][lane + 192] = v3;
    if (lane + 256 < n4)  s_row4[wb][lane + 256] = v4;
    if (lane + 320 < n4)  s_row4[wb][lane + 320] = v5;

    if (lane < rows) {
      const int p = p0 + lane;
      const float* x = (const float*)s_row4[wb] + lane * Cn;  // stride 21: 2-way, free
      float m = x[0];
      #pragma unroll
      for (int q = 1; q < Cn; q++) m = fmaxf(m, x[q]);
      float s = 0.0f;
      #pragma unroll
      for (int q = 0; q < Cn; q++) s += expf(x[q] - m);
      float lse = m + logf(s);
      ce0[(size_t)b * Pn + p] = lse - x[0];

      float4 d = ((const float4*)dbox)[p];
      float px1 = d.x - d.z * 0.5f, py1 = d.y - d.w * 0.5f;
      float px2 = d.x + d.z * 0.5f, py2 = d.y + d.w * 0.5f;
      float ap = d.z * d.w;
      float mv = -1.0f; int mj = 0;
      #pragma unroll
      for (int j = 0; j < On; j++) {
        float lx = fmaxf(s_tt[wb][j*5+0], px1);
        float ly = fmaxf(s_tt[wb][j*5+1], py1);
        float rx = fminf(s_tt[wb][j*5+2], px2);
        float ry = fminf(s_tt[wb][j*5+3], py2);
        float w = fmaxf(rx - lx, 0.0f), h = fmaxf(ry - ly, 0.0f);
        float inter = w * h;
        float ov = inter / (s_ar[wb][j] + ap - inter);
        if (ov > bestv[j]) { bestv[j] = ov; bestp[j] = p; }  // smallest p kept
        if (ov > mv) { mv = ov; mj = j; }                    // first max over j
      }
      pack[(size_t)b * Pn + p] =
          (unsigned char)(mj | ((mv >= 0.5f) ? 16 : 0));
    }
  }

  // per-truth argmax: wave shuffle reduce, then device atomicMax
  #pragma unroll
  for (int j = 0; j < On; j++) {
    float v = bestv[j]; int p = bestp[j];
    #pragma unroll
    for (int off = 32; off; off >>= 1) {
      float v2 = __shfl_down(v, off);
      int p2 = __shfl_down(p, off);
      argmax_combine(v, p, v2, p2);
    }
    if (lane == 0) {
      unsigned long long key;
      if (v < 0.0f) key = 0xC000000000000000ull;   // neutral, still beats poison
      else key = (((unsigned long long)(__float_as_uint(v) | 0xC0000000u)) << 32)
               | (unsigned long long)(0xFFFFFFFFu - (unsigned)p);
      atomicMax(&keys[b * On + j], key);
    }
  }
}

// ---------------------------------------------------------------------------
// Kernel B: per-image (128 blocks x 1024): forced matches, losses, exact top-k
// threshold via early-exit radix:
//   - hist[bin][wave] layout: 16 wave-copies of a bin live in 16 DISTINCT
//     banks ((bin*16+w)%32) -> concentrated exponent bins no longer serialize
//     across waves.
//   - bin scan: parallel suffix-sum by wave 0 (shuffles), not a tid==0 loop.
//   - after each pass, if surviving candidates <= 64, compact to LDS and do
//     exact rank-select in one wave (typ. 2 passes instead of 4).
// ---------------------------------------------------------------------------
__global__ __launch_bounds__(1024) void reduce_kernel(
    const float* __restrict__ loc, const float* __restrict__ conf,
    const float* __restrict__ dbox, const float* __restrict__ targets,
    const float* __restrict__ ce0, const unsigned char* __restrict__ pack,
    const unsigned long long* __restrict__ keys,
    unsigned int* __restrict__ res, float* __restrict__ out) {
  const int b = blockIdx.x;
  const int tid = threadIdx.x;
  const int wave = tid >> 6, lane = tid & 63;

  __shared__ float s_t[On * 5];
  __shared__ int s_bp[On];
  __shared__ unsigned hist[256 * 16];       // [bin][wave], 16 KB
  __shared__ unsigned s_col[256];
  __shared__ unsigned s_cand[64];
  __shared__ float s_redf[2][16];
  __shared__ int s_redi[16];
  __shared__ unsigned s_prefix;
  __shared__ int s_kk;
  __shared__ int s_cnt;
  __shared__ int s_cc;
  __shared__ int s_np;

  if (tid < On * 5) s_t[tid] = targets[(size_t)b * On * 5 + tid];
  if (tid < On)
    s_bp[tid] = (int)(0xFFFFFFFFu - (unsigned)(keys[b * On + tid] & 0xFFFFFFFFull));
  __syncthreads();

  float ce_r[9];
  float my_loc = 0.0f, my_cep = 0.0f; int my_np = 0;
  #pragma unroll
  for (int sI = 0; sI < 9; sI++) {
    ce_r[sI] = 0.0f;
    const int p = tid + 1024 * sI;
    if (p < Pn) {
      unsigned char pk = pack[(size_t)b * Pn + p];
      float c0 = ce0[(size_t)b * Pn + p];
      int pos = pk >> 4;
      int bt = pk & 15;
      #pragma unroll
      for (int j = 0; j < On; j++)
        if (s_bp[j] == p) { bt = j; pos = 1; }      // ascending: last j wins
      ce_r[sI] = pos ? 0.0f : c0;
      if (pos) {
        my_np++;
        const float* t = &s_t[bt * 5];
        int c = (int)t[4] + 1;
        const float* row = conf + ((size_t)b * Pn + p) * Cn;
        my_cep += c0 + row[0] - row[c];             // lse - x[c]
        float4 d = ((const float4*)dbox)[p];
        float mx1 = t[0], my1 = t[1], mx2 = t[2], my2 = t[3];
        float g0 = ((mx1 + mx2) * 0.5f - d.x) / (0.1f * d.z);
        float g1 = ((my1 + my2) * 0.5f - d.y) / (0.1f * d.w);
        float g2 = logf((mx2 - mx1) / d.z) / 0.2f;
        float g3 = logf((my2 - my1) / d.w) / 0.2f;
        float4 ld = ((const float4*)loc)[(size_t)b * Pn + p];
        float g[4] = {g0, g1, g2, g3};
        float l[4] = {ld.x, ld.y, ld.z, ld.w};
        #pragma unroll
        for (int q = 0; q < 4; q++) {
          float ad = fabsf(l[q] - g[q]);
          my_loc += (ad < 1.0f) ? 0.5f * ad * ad : ad - 0.5f;
        }
      }
    }
  }

  {
    int np = my_np;
    #pragma unroll
    for (int off = 32; off; off >>= 1) np += __shfl_down(np, off);
    if (lane == 0) s_redi[wave] = np;
  }
  __syncthreads();
  if (tid == 0) {
    int np = 0;
    #pragma unroll
    for (int w = 0; w < 16; w++) np += s_redi[w];
    s_np = np;
  }
  __syncthreads();

  // ---- exact k-th largest over register ce_neg values (all >= 0) ----
  const int k = min(s_np * 3, Pn);
  unsigned prefix = 0, maskb = 0;
  int kk = k;
  int cntc = Pn;
  for (int shift = 24; shift >= 0; shift -= 8) {
    if (cntc <= 64) break;                         // small-select path below
    // zero hist (4096 u32, one uint4 per thread)
    ((uint4*)hist)[tid] = make_uint4(0u, 0u, 0u, 0u);
    __syncthreads();
    #pragma unroll
    for (int sI = 0; sI < 9; sI++) {
      const int p = tid + 1024 * sI;
      if (p < Pn) {
        unsigned u = __float_as_uint(ce_r[sI]);
        if ((u & maskb) == prefix)
          atomicAdd(&hist[(((u >> shift) & 255u) << 4) + (unsigned)wave], 1u);
      }
    }
    __syncthreads();
    if (tid < 256) {
      unsigned c = 0;
      #pragma unroll
      for (int w = 0; w < 16; w++) c += hist[(tid << 4) + w];
      s_col[tid] = c;
    }
    __syncthreads();
    if (tid < 64) {
      // wave-0 parallel suffix scan over 256 bins (4 per lane)
      unsigned c0 = s_col[4 * tid + 0], c1 = s_col[4 * tid + 1];
      unsigned c2 = s_col[4 * tid + 2], c3 = s_col[4 * tid + 3];
      unsigned t0 = c0 + c1 + c2 + c3;
      unsigned S = t0;
      #pragma unroll
      for (int off = 1; off < 64; off <<= 1) {
        unsigned o = __shfl_down(S, off);
        if (tid + off < 64) S += o;
      }
      unsigned Snext = S - t0;                     // suffix of lanes > tid
      unsigned s3 = Snext + c3;
      unsigned s2 = s3 + c2;
      unsigned s1 = s2 + c1;
      unsigned s0 = s1 + c0;
      unsigned kk_u = (unsigned)kk;
      int chosen = -1; unsigned snx = 0, cc = 0;
      if (s3 >= kk_u && Snext < kk_u)      { chosen = 3; snx = Snext; cc = c3; }
      else if (s2 >= kk_u && s3 < kk_u)    { chosen = 2; snx = s3;    cc = c2; }
      else if (s1 >= kk_u && s2 < kk_u)    { chosen = 1; snx = s2;    cc = c1; }
      else if (s0 >= kk_u && s1 < kk_u)    { chosen = 0; snx = s1;    cc = c0; }
      if (chosen >= 0) {                           // exactly one lane hits
        s_prefix = prefix | ((unsigned)(4 * tid + chosen) << shift);
        s_kk = (int)(kk_u - snx);
        s_cnt = (int)cc;
      }
    }
    __syncthreads();
    prefix = s_prefix; kk = s_kk; cntc = s_cnt;
    maskb |= 255u << shift;
  }
  if (maskb != 0xFFFFFFFFu) {
    // <= 64 candidates share the prefix: exact rank-select in one wave
    if (tid == 0) s_cc = 0;
    __syncthreads();
    #pragma unroll
    for (int sI = 0; sI < 9; sI++) {
      const int p = tid + 1024 * sI;
      if (p < Pn) {
        unsigned u = __float_as_uint(ce_r[sI]);
        if ((u & maskb) == prefix) {
          int ix = atomicAdd(&s_cc, 1);
          s_cand[ix] = u;
        }
      }
    }
    __syncthreads();
    if (tid < 64) {
      int c = s_cc;
      if (tid < c) {
        unsigned v = s_cand[tid];
        int g = 0, e = 0;
        for (int i = 0; i < c; i++) {
          unsigned w = s_cand[i];
          g += (w > v); e += (w == v);
        }
        if (g < kk && kk <= g + e) s_prefix = v;   // tie-safe: all writers equal
      }
    }
    __syncthreads();
    prefix = s_prefix;
  }
  float T = __uint_as_float(prefix);

  float sum_gt = 0.0f; int cnt_gt = 0;
  #pragma unroll
  for (int sI = 0; sI < 9; sI++) {
    const int p = tid + 1024 * sI;
    if (p < Pn) {
      float x = ce_r[sI];
      if (x > T) { sum_gt += x; cnt_gt++; }
    }
  }
  #pragma unroll
  for (int off = 32; off; off >>= 1) {
    sum_gt += __shfl_down(sum_gt, off);
    cnt_gt += __shfl_down(cnt_gt, off);
    my_loc += __shfl_down(my_loc, off);
    my_cep += __shfl_down(my_cep, off);
  }
  if (lane == 0) {
    s_redf[0][wave] = my_loc; s_redf[1][wave] = sum_gt + my_cep; s_redi[wave] = cnt_gt;
  }
  __syncthreads();
  if (tid == 0) {
    float ll = 0.0f, lc = 0.0f; int cg = 0;
    #pragma unroll
    for (int w = 0; w < 16; w++) {
      ll += s_redf[0][w]; lc += s_redf[1][w]; cg += s_redi[w];
    }
    lc += (k > 0) ? (float)(k - cg) * T : 0.0f;
    // post partials (device-scope atomics; visible cross-XCD), then flag
    atomicExch(&res[b * 4 + 0], __float_as_uint(ll));
    atomicExch(&res[b * 4 + 1], __float_as_uint(lc));
    atomicExch(&res[b * 4 + 2], (unsigned)s_np);
    __threadfence();
    atomicExch(&res[b * 4 + 3], MAGIC);
  }

  // block 0, wave 0: gather all 128 partials and finalize (no extra kernel)
  if (b == 0 && tid < 64) {
    float ll = 0.0f, lc = 0.0f; int np = 0;
    #pragma unroll
    for (int h = 0; h < 2; h++) {
      const int i = tid + 64 * h;
      while (atomicAdd(&res[i * 4 + 3], 0u) != MAGIC) { __builtin_amdgcn_s_sleep(8); }
      ll += __uint_as_float(atomicAdd(&res[i * 4 + 0], 0u));
      lc += __uint_as_float(atomicAdd(&res[i * 4 + 1], 0u));
      np += (int)atomicAdd(&res[i * 4 + 2], 0u);
    }
    #pragma unroll
    for (int off = 32; off; off >>= 1) {
      ll += __shfl_down(ll, off);
      lc += __shfl_down(lc, off);
      np += __shfl_down(np, off);
    }
    if (tid == 0) {
      float fN = (float)np;
      out[0] = ll / fN;
      out[1] = lc / fN;
    }
  }
}

extern "C" void kernel_launch(void* const* d_in, const int* in_sizes, int n_in,
                              void* d_out, int out_size, void* d_ws, size_t ws_size,
                              hipStream_t stream) {
  const float* loc_data  = (const float*)d_in[0];
  const float* conf_data = (const float*)d_in[1];
  const float* dbox      = (const float*)d_in[2];
  const float* targets   = (const float*)d_in[3];
  float* out = (float*)d_out;

  char* ws = (char*)d_ws;
  float* ce0 = (float*)ws;                                           // B*P f32
  unsigned char* pack = (unsigned char*)(ws + (size_t)Bn * Pn * 4);  // B*P bytes
  unsigned long long* keys =
      (unsigned long long*)(ws + (size_t)Bn * Pn * 5);               // B*16 u64
  unsigned int* res = (unsigned int*)(ws + (size_t)Bn * Pn * 5 + Bn * On * 8); // B*4 u32

  stream_kernel<<<1024, 256, 0, stream>>>(conf_data, dbox, targets, ce0, pack, keys);
  reduce_kernel<<<Bn, 1024, 0, stream>>>(loc_data, conf_data, dbox, targets,
                                         ce0, pack, keys, res, out);
}